// Round 15
// baseline (47.768 us; speedup 1.0000x reference)
//
#include <hip/hip_runtime.h>
#include <hip/hip_bf16.h>
#include <cstddef>
#include <cstdint>

#define EPSV 1e-3f
#define LOG2E 1.4426950408889634f

using f32x4 = __attribute__((ext_vector_type(4))) float;

#if defined(__has_builtin)
#  if __has_builtin(__builtin_amdgcn_exp2f)
#    define EXP2F(v) __builtin_amdgcn_exp2f(v)
#  else
#    define EXP2F(v) exp2f(v)
#  endif
#else
#  define EXP2F(v) exp2f(v)
#endif

// 8-byte fp8 fragment (8 e4m3 values = 2 VGPRs)
union F8 { uint2 v; long long ll; };

// ---------------------------------------------------------------------------
// Kernel 1: projections (unchanged from R12/R14). 512 blocks x 32 pixels.
// theta/phi: [pix][32] fp8 e4m3 (theta pre-scaled by log2e). g CHUNK-MAJOR
// pre-shuffled: gpack[b][chunk=key>>5][d][32] fp8, within-chunk position
// kappa(h,i) = i<4 ? 4h+i : 16+4h+(i-4)  -> PV kmap-agnostic AND the attn
// G-fragment load is contiguous across lanes (512 B/instruction).
// ---------------------------------------------------------------------------
__global__ __launch_bounds__(256) void proj_kernel(
    const float* __restrict__ x,
    const float* __restrict__ gW, const float* __restrict__ gbias,
    const float* __restrict__ pW, const float* __restrict__ pbias,
    const float* __restrict__ tW, const float* __restrict__ tbias,
    uint8_t* __restrict__ thetab,
    uint8_t* __restrict__ phib,
    uint8_t* __restrict__ gshuf)
{
    __shared__ float lx[32*65];
    __shared__ __align__(16) float lw96[64*96];
    __shared__ float lbias[96];
    const int tid = threadIdx.x;
    const int pix0 = blockIdx.x * 32;

    #pragma unroll
    for (int j = 0; j < 8; ++j) {
        int idx = tid + 256*j;
        lx[(idx >> 6)*65 + (idx & 63)] = x[(size_t)pix0*64 + idx];
    }
    #pragma unroll
    for (int j = 0; j < 8; ++j) {
        int idx = tid + 256*j;
        int c = idx >> 5, o = idx & 31;
        lw96[c*96 + o]      = tW[idx];
        lw96[c*96 + 32 + o] = pW[idx];
        lw96[c*96 + 64 + o] = gW[idx];
    }
    if (tid < 32) { lbias[tid] = tbias[tid]; lbias[32+tid] = pbias[tid]; lbias[64+tid] = gbias[tid]; }
    __syncthreads();

    const int p  = tid & 31;
    const int og = tid >> 5;
    const int obase = og*12;
    float acc[12];
    #pragma unroll
    for (int j = 0; j < 12; ++j) acc[j] = 0.f;
    for (int c = 0; c < 64; ++c) {
        float xc = lx[p*65 + c];
        const float4* wp = (const float4*)&lw96[c*96 + obase];
        float4 w0 = wp[0], w1 = wp[1], w2 = wp[2];
        acc[0]  += xc * w0.x; acc[1]  += xc * w0.y; acc[2]  += xc * w0.z; acc[3]  += xc * w0.w;
        acc[4]  += xc * w1.x; acc[5]  += xc * w1.y; acc[6]  += xc * w1.z; acc[7]  += xc * w1.w;
        acc[8]  += xc * w2.x; acc[9]  += xc * w2.y; acc[10] += xc * w2.z; acc[11] += xc * w2.w;
    }
    const int pix = pix0 + p;
    const int b = pix >> 12;
    const int n = pix & 4095;
    const int chunk = n >> 5;
    const int loc = n & 31;
    const int t  = (loc >> 4) & 1;
    const int hh = (loc >> 2) & 3;
    const int jj = loc & 3;
    const int within = 8*hh + jj + 4*t;          // kappa position inside chunk
    #pragma unroll
    for (int j = 0; j < 12; ++j) {
        int o = obase + j;
        float v = acc[j] + lbias[o];
        float vs = (o < 32) ? v * LOG2E : v;
        int pk = __builtin_amdgcn_cvt_pk_fp8_f32(vs, vs, 0, false);
        uint8_t bv = (uint8_t)(pk & 0xFF);
        if (o < 32)       thetab[(size_t)pix*32 + o] = bv;
        else if (o < 64)  phib[(size_t)pix*32 + (o-32)] = bv;
        else              gshuf[((size_t)(b*128 + chunk)*32 + (o-64))*32 + within] = bv;
    }
}

// ---------------------------------------------------------------------------
// Kernel 2: fused flash-attention + output conv + BN partial stats.
// SLIM-WAVE restructure for 8 waves/SIMD: 512 blocks (4 batch x 128 qtiles
// of 32 queries) x 1024 threads; 16 waves = 2 q-tiles(16q) x 8 key-octants
// (512 keys). Each wave = R12's proven inner loop with the entire *B
// register family deleted (16 queries instead of 32): ~50-55 VGPR natural
// demand -> __launch_bounds__(1024, 8) caps at 64 WITHOUT spill ->
// 2 blocks/CU = 32 waves/CU = 8 waves/SIMD (R12 had 4).
// fp8 MFMA, depth-1 prefetch, chunk-major coalesced G. Stats transposed
// [128 stat-rows][512 blocks].
// ---------------------------------------------------------------------------
__global__ __launch_bounds__(1024, 8) void attn_kernel(
    const uint8_t* __restrict__ thetab,
    const uint8_t* __restrict__ phib,
    const uint8_t* __restrict__ gshuf,
    const float* __restrict__ wW, const float* __restrict__ wb,
    float* __restrict__ out, float* __restrict__ stats)
{
    __shared__ float yl[16][16][33];   // 33.8 KB
    __shared__ float lred[16][16];
    __shared__ float lwW[2048];
    __shared__ float lwb[64];
    const int tid  = threadIdx.x;
    const int wave = tid >> 6;
    const int lane = tid & 63;
    const int h = lane >> 4;
    const int r = lane & 15;
    const int blk = blockIdx.x;
    const int b = blk >> 7;            // 128 q-blocks per batch
    const int q0 = (blk & 127) * 32;
    const int qt = wave >> 3;          // q-tile 0/1 (16 queries each)
    const int kq = wave & 7;           // key octant (512 keys)
    const int qbase = q0 + qt*16;
    const size_t base = (size_t)b * 4096;

    #pragma unroll
    for (int j = 0; j < 2; ++j) lwW[tid + 1024*j] = wW[tid + 1024*j];
    if (tid < 64) lwb[tid] = wb[tid];

    F8 qaA;
    qaA.v = *(const uint2*)(thetab + (base + qbase + r)*32 + h*8);
    const uint8_t* phiB = phib  + base*32;
    const uint8_t* gB   = gshuf + (size_t)b*131072;   // b*128 chunks * 1024 B

    f32x4 y0A = {0,0,0,0}, y1A = {0,0,0,0};
    float lsA = 0.f;

    const int kbeg = kq * 512;
    const int kend = kbeg + 512;
    F8 ka, kb, g0, g1;
    ka.v = *(const uint2*)(phiB + (size_t)(kbeg + r)*32 + h*8);
    kb.v = *(const uint2*)(phiB + (size_t)(kbeg + 16 + r)*32 + h*8);
    g0.v = *(const uint2*)(gB + (size_t)(kbeg >> 5)*1024 + r*32 + 8*h);
    g1.v = *(const uint2*)(gB + (size_t)(kbeg >> 5)*1024 + (16 + r)*32 + 8*h);

    for (int kk = kbeg; kk < kend; kk += 32) {
        const int nk = (kk + 32 < kend) ? (kk + 32) : kbeg;   // depth-1 prefetch
        F8 ka2, kb2, g02, g12;
        ka2.v = *(const uint2*)(phiB + (size_t)(nk + r)*32 + h*8);
        kb2.v = *(const uint2*)(phiB + (size_t)(nk + 16 + r)*32 + h*8);
        g02.v = *(const uint2*)(gB + (size_t)(nk >> 5)*1024 + r*32 + 8*h);
        g12.v = *(const uint2*)(gB + (size_t)(nk >> 5)*1024 + (16 + r)*32 + 8*h);

        f32x4 z = {0,0,0,0};
        f32x4 s0A = __builtin_amdgcn_mfma_f32_16x16x32_fp8_fp8(ka.ll, qaA.ll, z, 0, 0, 0);
        f32x4 s1A = __builtin_amdgcn_mfma_f32_16x16x32_fp8_fp8(kb.ll, qaA.ll, z, 0, 0, 0);

        float pA0 = EXP2F(s0A[0]), pA1 = EXP2F(s0A[1]), pA2 = EXP2F(s0A[2]), pA3 = EXP2F(s0A[3]);
        float pA4 = EXP2F(s1A[0]), pA5 = EXP2F(s1A[1]), pA6 = EXP2F(s1A[2]), pA7 = EXP2F(s1A[3]);
        lsA += ((pA0+pA1)+(pA2+pA3)) + ((pA4+pA5)+(pA6+pA7));

        // pack P to fp8 in the SAME key order as gshuf's bake:
        // slots 0..7 = keys [4h..4h+3, 16+4h..16+4h+3]
        F8 paA;
        {
            int lo = __builtin_amdgcn_cvt_pk_fp8_f32(pA0, pA1, 0, false);
            lo     = __builtin_amdgcn_cvt_pk_fp8_f32(pA2, pA3, lo, true);
            int hi = __builtin_amdgcn_cvt_pk_fp8_f32(pA4, pA5, 0, false);
            hi     = __builtin_amdgcn_cvt_pk_fp8_f32(pA6, pA7, hi, true);
            paA.v.x = (uint32_t)lo; paA.v.y = (uint32_t)hi;
        }

        y0A = __builtin_amdgcn_mfma_f32_16x16x32_fp8_fp8(paA.ll, g0.ll, y0A, 0, 0, 0);
        y1A = __builtin_amdgcn_mfma_f32_16x16x32_fp8_fp8(paA.ll, g1.ll, y1A, 0, 0, 0);

        ka = ka2; kb = kb2; g0 = g02; g1 = g12;
    }

    lsA += __shfl_xor(lsA, 16); lsA += __shfl_xor(lsA, 32);

    #pragma unroll
    for (int gi = 0; gi < 4; ++gi) {
        yl[wave][4*h+gi][r]      = y0A[gi];   // [q 0..15][d 0..15]
        yl[wave][4*h+gi][16+r]   = y1A[gi];   // [q][d 16..31]
    }
    if (lane < 16) lred[wave][r] = lsA;
    __syncthreads();

    // Phase B: combine 8 key-octant waves per q-tile + normalize.
    // 1024 threads = 32 q x 32 d, one cell each; w=0 source cell is own cell.
    {
        const int q   = tid >> 5;          // 0..31
        const int d   = tid & 31;
        const int qt2 = q >> 4;
        const int ql  = q & 15;
        float a = 0.f, lq = 0.f;
        #pragma unroll
        for (int w = 0; w < 8; ++w) {
            a  += yl[qt2*8+w][ql][d];
            lq += lred[qt2*8+w][ql];
        }
        yl[qt2*8][ql][d] = a / lq;
    }
    __syncthreads();

    // Phase C: w_y = y @ w_W + w_b -> out (pre-BN); channel sum/sumsq.
    // p = tid&31 (pixel), cg = tid>>5 (0..31 -> 2 channels each).
    {
        const int p   = tid & 31;
        const int cg_ = tid >> 5;
        float acc[2];
        #pragma unroll
        for (int j = 0; j < 2; ++j) acc[j] = lwb[cg_*2 + j];
        for (int d = 0; d < 32; ++d) {
            float yv = yl[(p >> 4)*8][p & 15][d];
            #pragma unroll
            for (int j = 0; j < 2; ++j) acc[j] += yv * lwW[d*64 + cg_*2 + j];
        }
        float2 st = { acc[0], acc[1] };
        *(float2*)(out + (size_t)(base + q0 + p)*64 + cg_*2) = st;

        float s1[2], s2[2];
        #pragma unroll
        for (int j = 0; j < 2; ++j) { s1[j] = acc[j]; s2[j] = acc[j]*acc[j]; }
        #pragma unroll
        for (int m = 1; m <= 16; m <<= 1) {
            #pragma unroll
            for (int j = 0; j < 2; ++j) {
                s1[j] += __shfl_xor(s1[j], m);
                s2[j] += __shfl_xor(s2[j], m);
            }
        }
        if ((lane & 31) == 0) {             // lanes 0 and 32 of each wave
            #pragma unroll
            for (int j = 0; j < 2; ++j) {
                stats[(size_t)(cg_*2 + j)*512 + blk]        = s1[j];
                stats[(size_t)(64 + cg_*2 + j)*512 + blk]   = s2[j];
            }
        }
    }
}

// ---------------------------------------------------------------------------
// Kernel 3: fused BN-finalize + apply. stats is [128 stat-rows][512 blocks]
// -> contiguous float4 reduce (4 threads/channel x 32 float4 each).
// Then out = x + sc*w_y + sh (w_y currently in d_out).
// ---------------------------------------------------------------------------
__global__ __launch_bounds__(256) void apply_kernel(
    const float* __restrict__ stats,
    const float* __restrict__ gamma,
    const float* __restrict__ beta,
    const float* __restrict__ x,
    float* __restrict__ out)
{
    __shared__ float sums1[64];
    __shared__ float sums2[64];
    __shared__ __align__(16) float params[128];
    const int tid = threadIdx.x;
    {
        const int c = tid >> 2;        // 0..63
        const int part = tid & 3;      // 0..3 -> 32 float4 each
        const float4* st4 = (const float4*)stats;
        float s1 = 0.f, s2 = 0.f;
        #pragma unroll
        for (int j = 0; j < 32; ++j) {
            float4 v = st4[c*128 + part*32 + j];
            s1 += (v.x + v.y) + (v.z + v.w);
        }
        #pragma unroll
        for (int j = 0; j < 32; ++j) {
            float4 v = st4[(64 + c)*128 + part*32 + j];
            s2 += (v.x + v.y) + (v.z + v.w);
        }
        s1 += __shfl_xor(s1, 1); s1 += __shfl_xor(s1, 2);
        s2 += __shfl_xor(s2, 1); s2 += __shfl_xor(s2, 2);
        if (part == 0) { sums1[c] = s1; sums2[c] = s2; }
    }
    __syncthreads();
    if (tid < 64) {
        float mean = sums1[tid] * (1.0f/16384.0f);
        float var  = sums2[tid] * (1.0f/16384.0f) - mean*mean;
        float sc = gamma[tid] * rsqrtf(var + EPSV);
        params[tid]      = sc;
        params[64 + tid] = beta[tid] - mean*sc;
    }
    __syncthreads();

    const float4* x4 = (const float4*)x;
    float4* o4 = (float4*)out;
    #pragma unroll
    for (int j = 0; j < 4; ++j) {
        int i4 = blockIdx.x*1024 + tid + 256*j;   // 262144 float4s total
        int cb = (i4 & 15) * 4;
        float4 v  = o4[i4];
        float4 xv = x4[i4];
        float4 sc = *(const float4*)&params[cb];
        float4 sh = *(const float4*)&params[64 + cb];
        float4 rr;
        rr.x = xv.x + sc.x*v.x + sh.x;
        rr.y = xv.y + sc.y*v.y + sh.y;
        rr.z = xv.z + sc.z*v.z + sh.z;
        rr.w = xv.w + sc.w*v.w + sh.w;
        o4[i4] = rr;
    }
}

// ---------------------------------------------------------------------------
extern "C" void kernel_launch(void* const* d_in, const int* in_sizes, int n_in,
                              void* d_out, int out_size, void* d_ws, size_t ws_size,
                              hipStream_t stream)
{
    const float* x     = (const float*)d_in[0];
    const float* gW    = (const float*)d_in[1];
    const float* gb    = (const float*)d_in[2];
    const float* pW    = (const float*)d_in[3];
    const float* pb    = (const float*)d_in[4];
    const float* tW    = (const float*)d_in[5];
    const float* tb    = (const float*)d_in[6];
    const float* wW    = (const float*)d_in[7];
    const float* wb    = (const float*)d_in[8];
    const float* gamma = (const float*)d_in[9];
    const float* beta  = (const float*)d_in[10];
    float* out = (float*)d_out;

    char* w = (char*)d_ws;
    uint8_t* thetab = (uint8_t*)(w);                               // 512 KB
    uint8_t* phib   = (uint8_t*)(w + (1u<<19));                    // 512 KB
    uint8_t* gshuf  = (uint8_t*)(w + (2u<<19));                    // 512 KB
    float* stats    = (float*)(w + (3u<<19));                      // 256 KB

    proj_kernel<<<512, 256, 0, stream>>>(x, gW, gb, pW, pb, tW, tb, thetab, phib, gshuf);
    attn_kernel<<<512, 1024, 0, stream>>>(thetab, phib, gshuf, wW, wb, out, stats);
    apply_kernel<<<256, 256, 0, stream>>>(stats, gamma, beta, x, out);
}

// Round 16
// 37.536 us; speedup vs baseline: 1.2726x; 1.2726x over previous
//
#include <hip/hip_runtime.h>
#include <hip/hip_bf16.h>
#include <cstddef>
#include <cstdint>

#define EPSV 1e-3f
#define LOG2E 1.4426950408889634f

using f32x4 = __attribute__((ext_vector_type(4))) float;

#if defined(__has_builtin)
#  if __has_builtin(__builtin_amdgcn_exp2f)
#    define EXP2F(v) __builtin_amdgcn_exp2f(v)
#  else
#    define EXP2F(v) exp2f(v)
#  endif
#else
#  define EXP2F(v) exp2f(v)
#endif

// 8-byte fp8 fragment (8 e4m3 values = 2 VGPRs)
union F8 { uint2 v; long long ll; };

// ---------------------------------------------------------------------------
// Kernel 1: projections. 512 blocks x 32 pixels. theta: [pix][32] fp8 e4m3
// (pre-scaled by log2e). phi and g stored PAIR-PACKED chunk-major so the attn
// kernel loads BOTH fragments of a pair with ONE dwordx4 (16B/lane, 1KB/wave
// fully contiguous):
//   kpack[b][chunk][(h*16+r)*16]: bytes0-7 = phi[key kk+r][feat 8h..8h+7],
//                                 bytes8-15 = phi[key kk+16+r][same feats]
//   gpack[b][chunk][(h*16+r)*16]: bytes0-7 = G[d=r][kappa keys 8h..8h+7],
//                                 bytes8-15 = G[d=16+r][same keys]
// kappa(h,i) = i<4 ? 4h+i : 16+4h+(i-4) — same bake as rounds 1-15
// (P-register key order, dtype-independent C/D layout) -> PV kmap-agnostic.
// ---------------------------------------------------------------------------
__global__ __launch_bounds__(256) void proj_kernel(
    const float* __restrict__ x,
    const float* __restrict__ gW, const float* __restrict__ gbias,
    const float* __restrict__ pW, const float* __restrict__ pbias,
    const float* __restrict__ tW, const float* __restrict__ tbias,
    uint8_t* __restrict__ thetab,
    uint8_t* __restrict__ phib,
    uint8_t* __restrict__ gshuf)
{
    __shared__ float lx[32*65];
    __shared__ __align__(16) float lw96[64*96];
    __shared__ float lbias[96];
    const int tid = threadIdx.x;
    const int pix0 = blockIdx.x * 32;

    #pragma unroll
    for (int j = 0; j < 8; ++j) {
        int idx = tid + 256*j;
        lx[(idx >> 6)*65 + (idx & 63)] = x[(size_t)pix0*64 + idx];
    }
    #pragma unroll
    for (int j = 0; j < 8; ++j) {
        int idx = tid + 256*j;
        int c = idx >> 5, o = idx & 31;
        lw96[c*96 + o]      = tW[idx];
        lw96[c*96 + 32 + o] = pW[idx];
        lw96[c*96 + 64 + o] = gW[idx];
    }
    if (tid < 32) { lbias[tid] = tbias[tid]; lbias[32+tid] = pbias[tid]; lbias[64+tid] = gbias[tid]; }
    __syncthreads();

    const int p  = tid & 31;
    const int og = tid >> 5;
    const int obase = og*12;
    float acc[12];
    #pragma unroll
    for (int j = 0; j < 12; ++j) acc[j] = 0.f;
    for (int c = 0; c < 64; ++c) {
        float xc = lx[p*65 + c];
        const float4* wp = (const float4*)&lw96[c*96 + obase];
        float4 w0 = wp[0], w1 = wp[1], w2 = wp[2];
        acc[0]  += xc * w0.x; acc[1]  += xc * w0.y; acc[2]  += xc * w0.z; acc[3]  += xc * w0.w;
        acc[4]  += xc * w1.x; acc[5]  += xc * w1.y; acc[6]  += xc * w1.z; acc[7]  += xc * w1.w;
        acc[8]  += xc * w2.x; acc[9]  += xc * w2.y; acc[10] += xc * w2.z; acc[11] += xc * w2.w;
    }
    const int pix = pix0 + p;
    const int b = pix >> 12;
    const int n = pix & 4095;
    const int chunk = n >> 5;
    const int loc = n & 31;
    const size_t cb1024 = (size_t)(b*128 + chunk)*1024;
    // kappa position for G (key-derived)
    const int t  = (loc >> 4) & 1;
    const int hh = (loc >> 2) & 3;
    const int jj = loc & 3;
    const int w_ = 8*hh + jj + 4*t;              // 0..31, kappa slot of this key
    #pragma unroll
    for (int j = 0; j < 12; ++j) {
        int o = obase + j;
        float v = acc[j] + lbias[o];
        float vs = (o < 32) ? v * LOG2E : v;
        int pk = __builtin_amdgcn_cvt_pk_fp8_f32(vs, vs, 0, false);
        uint8_t bv = (uint8_t)(pk & 0xFF);
        if (o < 32) {
            thetab[(size_t)pix*32 + o] = bv;
        } else if (o < 64) {
            // phi pair-pack: feature f, key loc
            int f = o - 32;
            int fh = f >> 3, fb = f & 7;
            phib[cb1024 + (size_t)(fh*16 + (loc & 15))*16 + ((loc & 16) ? 8 : 0) + fb] = bv;
        } else {
            // g pair-pack: dim d, kappa slot w_
            int d = o - 64;
            gshuf[cb1024 + (size_t)((w_ >> 3)*16 + (d & 15))*16 + ((d & 16) ? 8 : 0) + (w_ & 7)] = bv;
        }
    }
}

// ---------------------------------------------------------------------------
// Kernel 2: fused flash-attention + output conv + BN partial stats.
// R14 structure (proven 37.1us; 256 blocks x 1024 threads, 16 waves =
// 2 q-halves x 8 key-octants, PV-lag pipeline, fp8 MFMA) with ONE change:
// PAIRED LOADS — (ka|kb) and (g0|g1) each arrive as a single dwordx4
// (16B/lane, 1KB/wave contiguous). Load instructions per chunk: 4 -> 2
// (R15 showed load count is the binding cost: doubling it cost +10us).
// Stats transposed [128 stat-rows][256 blocks].
// ---------------------------------------------------------------------------
__global__ __launch_bounds__(1024, 4) void attn_kernel(
    const uint8_t* __restrict__ thetab,
    const uint8_t* __restrict__ phib,
    const uint8_t* __restrict__ gshuf,
    const float* __restrict__ wW, const float* __restrict__ wb,
    float* __restrict__ out, float* __restrict__ stats)
{
    __shared__ float yl[16][32][33];   // 67.6 KB
    __shared__ float lred[16][32];
    __shared__ float lwW[2048];
    __shared__ float lwb[64];
    const int tid  = threadIdx.x;
    const int wave = tid >> 6;
    const int lane = tid & 63;
    const int h = lane >> 4;
    const int r = lane & 15;
    const int blk = blockIdx.x;
    const int b = blk >> 6;            // 64 q-blocks per batch
    const int q0 = (blk & 63) * 64;
    const int qh = wave >> 3;          // query half 0/1
    const int kq = wave & 7;           // key octant
    const int qbase = q0 + qh*32;
    const size_t base = (size_t)b * 4096;

    #pragma unroll
    for (int j = 0; j < 2; ++j) lwW[tid + 1024*j] = wW[tid + 1024*j];
    if (tid < 64) lwb[tid] = wb[tid];

    F8 qaA, qaB;
    qaA.v = *(const uint2*)(thetab + (base + qbase + r)*32 + h*8);
    qaB.v = *(const uint2*)(thetab + (base + qbase + 16 + r)*32 + h*8);
    const uint8_t* phiB = phib  + (size_t)b*131072;   // 128 chunks * 1024 B
    const uint8_t* gB   = gshuf + (size_t)b*131072;
    const int loff = (h*16 + r)*16;                   // lane slot in pair-pack

    f32x4 y0A = {0,0,0,0}, y1A = {0,0,0,0};
    f32x4 y0B = {0,0,0,0}, y1B = {0,0,0,0};
    float lsA = 0.f, lsB = 0.f;

    const int cbeg = kq * 16;          // first chunk of this octant

    // QK(chunk) + exp + pack -> pa (key order matches gshuf bake:
    // slots 0..7 = keys [4h..4h+3, 16+4h..16+4h+3])
    auto QKEXP = [&](const uint4& kf, F8& pA_, F8& pB_) {
        F8 ka_, kb_;
        ka_.v.x = kf.x; ka_.v.y = kf.y;
        kb_.v.x = kf.z; kb_.v.y = kf.w;
        f32x4 z = {0,0,0,0};
        f32x4 s0A = __builtin_amdgcn_mfma_f32_16x16x32_fp8_fp8(ka_.ll, qaA.ll, z, 0, 0, 0);
        f32x4 s1A = __builtin_amdgcn_mfma_f32_16x16x32_fp8_fp8(kb_.ll, qaA.ll, z, 0, 0, 0);
        f32x4 s0B = __builtin_amdgcn_mfma_f32_16x16x32_fp8_fp8(ka_.ll, qaB.ll, z, 0, 0, 0);
        f32x4 s1B = __builtin_amdgcn_mfma_f32_16x16x32_fp8_fp8(kb_.ll, qaB.ll, z, 0, 0, 0);

        float pA0 = EXP2F(s0A[0]), pA1 = EXP2F(s0A[1]), pA2 = EXP2F(s0A[2]), pA3 = EXP2F(s0A[3]);
        float pA4 = EXP2F(s1A[0]), pA5 = EXP2F(s1A[1]), pA6 = EXP2F(s1A[2]), pA7 = EXP2F(s1A[3]);
        float pB0 = EXP2F(s0B[0]), pB1 = EXP2F(s0B[1]), pB2 = EXP2F(s0B[2]), pB3 = EXP2F(s0B[3]);
        float pB4 = EXP2F(s1B[0]), pB5 = EXP2F(s1B[1]), pB6 = EXP2F(s1B[2]), pB7 = EXP2F(s1B[3]);
        lsA += ((pA0+pA1)+(pA2+pA3)) + ((pA4+pA5)+(pA6+pA7));
        lsB += ((pB0+pB1)+(pB2+pB3)) + ((pB4+pB5)+(pB6+pB7));

        int lo = __builtin_amdgcn_cvt_pk_fp8_f32(pA0, pA1, 0, false);
        lo     = __builtin_amdgcn_cvt_pk_fp8_f32(pA2, pA3, lo, true);
        int hi = __builtin_amdgcn_cvt_pk_fp8_f32(pA4, pA5, 0, false);
        hi     = __builtin_amdgcn_cvt_pk_fp8_f32(pA6, pA7, hi, true);
        pA_.v.x = (uint32_t)lo; pA_.v.y = (uint32_t)hi;
        lo = __builtin_amdgcn_cvt_pk_fp8_f32(pB0, pB1, 0, false);
        lo = __builtin_amdgcn_cvt_pk_fp8_f32(pB2, pB3, lo, true);
        hi = __builtin_amdgcn_cvt_pk_fp8_f32(pB4, pB5, 0, false);
        hi = __builtin_amdgcn_cvt_pk_fp8_f32(pB6, pB7, hi, true);
        pB_.v.x = (uint32_t)lo; pB_.v.y = (uint32_t)hi;
    };

    auto PV = [&](const F8& pA_, const F8& pB_, const uint4& gf) {
        F8 g0_, g1_;
        g0_.v.x = gf.x; g0_.v.y = gf.y;
        g1_.v.x = gf.z; g1_.v.y = gf.w;
        y0A = __builtin_amdgcn_mfma_f32_16x16x32_fp8_fp8(pA_.ll, g0_.ll, y0A, 0, 0, 0);
        y1A = __builtin_amdgcn_mfma_f32_16x16x32_fp8_fp8(pA_.ll, g1_.ll, y1A, 0, 0, 0);
        y0B = __builtin_amdgcn_mfma_f32_16x16x32_fp8_fp8(pB_.ll, g0_.ll, y0B, 0, 0, 0);
        y1B = __builtin_amdgcn_mfma_f32_16x16x32_fp8_fp8(pB_.ll, g1_.ll, y1B, 0, 0, 0);
    };

    // staging: kC = K-pair for the chunk whose QK runs this iter;
    // gP = G-pair for the chunk whose PV runs this iter; gC = one ahead.
    uint4 kC, kN, gP, gC, gN;
    kC = *(const uint4*)(phiB + (size_t)cbeg*1024 + loff);
    gP = *(const uint4*)(gB   + (size_t)cbeg*1024 + loff);
    kN = *(const uint4*)(phiB + (size_t)(cbeg + 1)*1024 + loff);
    gC = *(const uint4*)(gB   + (size_t)(cbeg + 1)*1024 + loff);

    F8 paA0, paB0;
    QKEXP(kC, paA0, paB0);             // chunk cbeg
    kC = kN;

    for (int t = 1; t < 16; ++t) {
        const int nc = (t + 1 < 16) ? cbeg + t + 1 : cbeg;   // dummy wrap at end
        kN = *(const uint4*)(phiB + (size_t)nc*1024 + loff);
        gN = *(const uint4*)(gB   + (size_t)nc*1024 + loff);

        PV(paA0, paB0, gP);            // PV for chunk t-1 (indep of this QK/exp)
        QKEXP(kC, paA0, paB0);         // QK + exp + pack for chunk t

        kC = kN;
        gP = gC; gC = gN;
    }
    PV(paA0, paB0, gP);                // epilogue: PV for chunk cbeg+15

    lsA += __shfl_xor(lsA, 16); lsA += __shfl_xor(lsA, 32);
    lsB += __shfl_xor(lsB, 16); lsB += __shfl_xor(lsB, 32);

    #pragma unroll
    for (int gi = 0; gi < 4; ++gi) {
        yl[wave][4*h+gi][r]       = y0A[gi];
        yl[wave][4*h+gi][16+r]    = y1A[gi];
        yl[wave][16+4*h+gi][r]    = y0B[gi];
        yl[wave][16+4*h+gi][16+r] = y1B[gi];
    }
    if (lane < 16) { lred[wave][r] = lsA; lred[wave][16+r] = lsB; }
    __syncthreads();

    // Phase B: combine 8 key-octant waves per query half + normalize.
    {
        const int q   = tid >> 4;
        const int d2  = (tid & 15) * 2;
        const int qh2 = q >> 5;
        const int ql  = q & 31;
        float a0=0.f, a1=0.f, lq=0.f;
        #pragma unroll
        for (int w = 0; w < 8; ++w) {
            a0 += yl[qh2*8+w][ql][d2];
            a1 += yl[qh2*8+w][ql][d2+1];
            lq += lred[qh2*8+w][ql];
        }
        float inv = 1.0f / lq;
        yl[qh2*8][ql][d2]   = a0*inv;
        yl[qh2*8][ql][d2+1] = a1*inv;
    }
    __syncthreads();

    // Phase C: w_y = y @ w_W + w_b -> out (pre-BN); channel sum/sumsq.
    {
        const int p   = lane;              // pixel within block (0..63)
        const int cg_ = wave;              // channel group (0..15)
        float acc[4];
        #pragma unroll
        for (int j = 0; j < 4; ++j) acc[j] = lwb[cg_*4 + j];
        for (int d = 0; d < 32; ++d) {
            float yv = yl[(p >> 5)*8][p & 31][d];
            #pragma unroll
            for (int j = 0; j < 4; ++j) acc[j] += yv * lwW[d*64 + cg_*4 + j];
        }
        *(float4*)(out + (size_t)(base + q0 + p)*64 + cg_*4) = *(float4*)&acc[0];

        float s1[4], s2[4];
        #pragma unroll
        for (int j = 0; j < 4; ++j) { s1[j] = acc[j]; s2[j] = acc[j]*acc[j]; }
        #pragma unroll
        for (int m = 1; m <= 32; m <<= 1) {
            #pragma unroll
            for (int j = 0; j < 4; ++j) {
                s1[j] += __shfl_xor(s1[j], m);
                s2[j] += __shfl_xor(s2[j], m);
            }
        }
        if (lane == 0) {                    // transposed: stats[stat_row][block]
            #pragma unroll
            for (int j = 0; j < 4; ++j) {
                stats[(size_t)(cg_*4 + j)*256 + blk]        = s1[j];
                stats[(size_t)(64 + cg_*4 + j)*256 + blk]   = s2[j];
            }
        }
    }
}

// ---------------------------------------------------------------------------
// Kernel 3: fused BN-finalize + apply (unchanged from R12/R14).
// ---------------------------------------------------------------------------
__global__ __launch_bounds__(256) void apply_kernel(
    const float* __restrict__ stats,
    const float* __restrict__ gamma,
    const float* __restrict__ beta,
    const float* __restrict__ x,
    float* __restrict__ out)
{
    __shared__ float sums1[64];
    __shared__ float sums2[64];
    __shared__ __align__(16) float params[128];
    const int tid = threadIdx.x;
    {
        const int c = tid >> 2;        // 0..63
        const int part = tid & 3;      // 0..3 -> blocks part*64..+63
        const float4* st4 = (const float4*)stats;
        float s1 = 0.f, s2 = 0.f;
        #pragma unroll
        for (int j = 0; j < 16; ++j) {
            float4 v = st4[c*64 + part*16 + j];
            s1 += (v.x + v.y) + (v.z + v.w);
        }
        #pragma unroll
        for (int j = 0; j < 16; ++j) {
            float4 v = st4[(64 + c)*64 + part*16 + j];
            s2 += (v.x + v.y) + (v.z + v.w);
        }
        s1 += __shfl_xor(s1, 1); s1 += __shfl_xor(s1, 2);
        s2 += __shfl_xor(s2, 1); s2 += __shfl_xor(s2, 2);
        if (part == 0) { sums1[c] = s1; sums2[c] = s2; }
    }
    __syncthreads();
    if (tid < 64) {
        float mean = sums1[tid] * (1.0f/16384.0f);
        float var  = sums2[tid] * (1.0f/16384.0f) - mean*mean;
        float sc = gamma[tid] * rsqrtf(var + EPSV);
        params[tid]      = sc;
        params[64 + tid] = beta[tid] - mean*sc;
    }
    __syncthreads();

    const float4* x4 = (const float4*)x;
    float4* o4 = (float4*)out;
    #pragma unroll
    for (int j = 0; j < 4; ++j) {
        int i4 = blockIdx.x*1024 + tid + 256*j;   // 262144 float4s total
        int cb = (i4 & 15) * 4;
        float4 v  = o4[i4];
        float4 xv = x4[i4];
        float4 sc = *(const float4*)&params[cb];
        float4 sh = *(const float4*)&params[64 + cb];
        float4 rr;
        rr.x = xv.x + sc.x*v.x + sh.x;
        rr.y = xv.y + sc.y*v.y + sh.y;
        rr.z = xv.z + sc.z*v.z + sh.z;
        rr.w = xv.w + sc.w*v.w + sh.w;
        o4[i4] = rr;
    }
}

// ---------------------------------------------------------------------------
extern "C" void kernel_launch(void* const* d_in, const int* in_sizes, int n_in,
                              void* d_out, int out_size, void* d_ws, size_t ws_size,
                              hipStream_t stream)
{
    const float* x     = (const float*)d_in[0];
    const float* gW    = (const float*)d_in[1];
    const float* gb    = (const float*)d_in[2];
    const float* pW    = (const float*)d_in[3];
    const float* pb    = (const float*)d_in[4];
    const float* tW    = (const float*)d_in[5];
    const float* tb    = (const float*)d_in[6];
    const float* wW    = (const float*)d_in[7];
    const float* wb    = (const float*)d_in[8];
    const float* gamma = (const float*)d_in[9];
    const float* beta  = (const float*)d_in[10];
    float* out = (float*)d_out;

    char* w = (char*)d_ws;
    uint8_t* thetab = (uint8_t*)(w);                               // 512 KB
    uint8_t* phib   = (uint8_t*)(w + (1u<<19));                    // 512 KB
    uint8_t* gshuf  = (uint8_t*)(w + (2u<<19));                    // 512 KB
    float* stats    = (float*)(w + (3u<<19));                      // 128 KB

    proj_kernel<<<512, 256, 0, stream>>>(x, gW, gb, pW, pb, tW, tb, thetab, phib, gshuf);
    attn_kernel<<<256, 1024, 0, stream>>>(thetab, phib, gshuf, wW, wb, out, stats);
    apply_kernel<<<256, 256, 0, stream>>>(stats, gamma, beta, x, out);
}

// Round 17
// 33.721 us; speedup vs baseline: 1.4166x; 1.1131x over previous
//
#include <hip/hip_runtime.h>
#include <hip/hip_bf16.h>
#include <cstddef>
#include <cstdint>

#define EPSV 1e-3f
#define LOG2E 1.4426950408889634f

using f32x4 = __attribute__((ext_vector_type(4))) float;
using bh8   = __attribute__((ext_vector_type(8))) short;   // 8 bf16

#if defined(__has_builtin)
#  if __has_builtin(__builtin_amdgcn_exp2f)
#    define EXP2F(v) __builtin_amdgcn_exp2f(v)
#  else
#    define EXP2F(v) exp2f(v)
#  endif
#else
#  define EXP2F(v) exp2f(v)
#endif

// 8-byte fp8 fragment (8 e4m3 values = 2 VGPRs)
union F8 { uint2 v; long long ll; };
union BH { uint32_t u[4]; bh8 v; };

// packed f32x2 -> bf16x2 (RNE), one VALU op
static __device__ __forceinline__ uint32_t cvtpkbf(float lo, float hi) {
    uint32_t r;
    asm("v_cvt_pk_bf16_f32 %0, %1, %2" : "=v"(r) : "v"(lo), "v"(hi));
    return r;
}

// ---------------------------------------------------------------------------
// Kernel 1: projections via MFMA. 512 blocks x 32 pixels (= exactly one
// 32-key chunk). [32pix x 64c] @ [64c x 96o] as 12 16x16 tiles x 2 K-steps
// = 24 bf16 MFMAs/block (replaces the LDS-throughput-bound FMA loop:
// 192 ds_read_b128/thread -> 6). W staged transposed bf16 [96][72] in LDS;
// x A-fragments loaded straight from global (4 float4 + cvt_pk per wave).
// Outputs (identical layout to R16): theta [pix][32] fp8 e4m3 (pre-scaled
// log2e); phi/g PAIR-PACKED chunk-major (one dwordx4 in attn fetches both
// fragments of a pair):
//   kpack[b][chunk][(h*16+r)*16]: bytes0-7 = phi[key kk+r][feat 8h..],
//                                 bytes8-15 = phi[key kk+16+r][same]
//   gpack[b][chunk][(h*16+r)*16]: bytes0-7 = G[d=r][kappa keys 8h..],
//                                 bytes8-15 = G[d=16+r][same]
// kappa(h,i) = i<4 ? 4h+i : 16+4h+(i-4) — P-register key order -> PV
// kmap-agnostic (verified rounds 1-16).
// MFMA layout (verified R1): A=1st operand -> M(rows), B=2nd -> N(cols);
// D: col = lane&15, row = 4*(lane>>4)+gi; A/B frags share one kmap.
// ---------------------------------------------------------------------------
__global__ __launch_bounds__(256) void proj_kernel(
    const float* __restrict__ x,
    const float* __restrict__ gW, const float* __restrict__ gbias,
    const float* __restrict__ pW, const float* __restrict__ pbias,
    const float* __restrict__ tW, const float* __restrict__ tbias,
    uint8_t* __restrict__ thetab,
    uint8_t* __restrict__ phib,
    uint8_t* __restrict__ gshuf)
{
    __shared__ __align__(16) __hip_bfloat16 wbuf[96*72];   // [o][c], 72-padded
    __shared__ float lbias[96];
    const int tid = threadIdx.x;
    const int pix0 = blockIdx.x * 32;

    // stage W transposed as bf16: wbuf[o][c] <- {tW,pW,gW}[c][o%32]
    #pragma unroll
    for (int j = 0; j < 8; ++j) {
        int idx = tid + 256*j;          // 0..2047
        int c = idx >> 5, ol = idx & 31;
        wbuf[(ol)*72 + c]      = __float2bfloat16(tW[idx]);
        wbuf[(32+ol)*72 + c]   = __float2bfloat16(pW[idx]);
        wbuf[(64+ol)*72 + c]   = __float2bfloat16(gW[idx]);
    }
    if (tid < 32) { lbias[tid] = tbias[tid]; lbias[32+tid] = pbias[tid]; lbias[64+tid] = gbias[tid]; }
    __syncthreads();

    const int wv = tid >> 6;
    const int ln = tid & 63;
    const int h = ln >> 4;
    const int r = ln & 15;
    const int mt = wv & 1;              // M-tile of this wave (fixed)

    // A-fragments for K=0..31 and K=32..63, straight from global x (f32->bf16)
    BH a0, a1;
    {
        const float* xr = x + (size_t)(pix0 + mt*16 + r)*64 + h*8;
        float4 f0 = *(const float4*)xr;
        float4 f1 = *(const float4*)(xr + 4);
        a0.u[0] = cvtpkbf(f0.x, f0.y); a0.u[1] = cvtpkbf(f0.z, f0.w);
        a0.u[2] = cvtpkbf(f1.x, f1.y); a0.u[3] = cvtpkbf(f1.z, f1.w);
        float4 f2 = *(const float4*)(xr + 32);
        float4 f3 = *(const float4*)(xr + 36);
        a1.u[0] = cvtpkbf(f2.x, f2.y); a1.u[1] = cvtpkbf(f2.z, f2.w);
        a1.u[2] = cvtpkbf(f3.x, f3.y); a1.u[3] = cvtpkbf(f3.z, f3.w);
    }

    const int b = pix0 >> 12;
    const int chunk = (pix0 & 4095) >> 5;
    const size_t cb1024 = (size_t)(b*128 + chunk)*1024;

    // tiles T = wv, wv+4, wv+8  (T&1 == wv&1 == mt for all)
    for (int T = wv; T < 12; T += 4) {
        const int nt = T >> 1;
        bh8 b0 = *(const bh8*)&wbuf[(nt*16 + r)*72 + h*8];
        bh8 b1 = *(const bh8*)&wbuf[(nt*16 + r)*72 + 32 + h*8];
        f32x4 cc = {0.f, 0.f, 0.f, 0.f};
        cc = __builtin_amdgcn_mfma_f32_16x16x32_bf16(a0.v, b0, cc, 0, 0, 0);
        cc = __builtin_amdgcn_mfma_f32_16x16x32_bf16(a1.v, b1, cc, 0, 0, 0);

        const int o = nt*16 + r;
        const float bias = lbias[o];
        if (o < 32) {
            #pragma unroll
            for (int gi = 0; gi < 4; ++gi) {
                int pl = mt*16 + 4*h + gi;
                float v = (cc[gi] + bias) * LOG2E;
                int pk = __builtin_amdgcn_cvt_pk_fp8_f32(v, v, 0, false);
                thetab[(size_t)(pix0 + pl)*32 + o] = (uint8_t)(pk & 0xFF);
            }
        } else if (o < 64) {
            const int f = o - 32;
            const int fh = f >> 3, fb = f & 7;
            #pragma unroll
            for (int gi = 0; gi < 4; ++gi) {
                int loc = mt*16 + 4*h + gi;
                float v = cc[gi] + bias;
                int pk = __builtin_amdgcn_cvt_pk_fp8_f32(v, v, 0, false);
                phib[cb1024 + (size_t)(fh*16 + (loc & 15))*16 + ((loc & 16) ? 8 : 0) + fb]
                    = (uint8_t)(pk & 0xFF);
            }
        } else {
            const int d = o - 64;
            #pragma unroll
            for (int gi = 0; gi < 4; ++gi) {
                int loc = mt*16 + 4*h + gi;
                int t_ = (loc >> 4) & 1;
                int hh = (loc >> 2) & 3;
                int jj = loc & 3;
                int w_ = 8*hh + jj + 4*t_;
                float v = cc[gi] + bias;
                int pk = __builtin_amdgcn_cvt_pk_fp8_f32(v, v, 0, false);
                gshuf[cb1024 + (size_t)((w_ >> 3)*16 + (d & 15))*16 + ((d & 16) ? 8 : 0) + (w_ & 7)]
                    = (uint8_t)(pk & 0xFF);
            }
        }
    }
}

// ---------------------------------------------------------------------------
// Kernel 2: fused flash-attention + output conv + BN partial stats.
// BYTE-IDENTICAL to R16 (37.5us): 256 blocks x 1024 threads, 16 waves =
// 2 q-halves x 8 key-octants, PV-lag pipeline, fp8 MFMA, paired dwordx4
// loads (2/chunk). Stats transposed [128 stat-rows][256 blocks].
// ---------------------------------------------------------------------------
__global__ __launch_bounds__(1024, 4) void attn_kernel(
    const uint8_t* __restrict__ thetab,
    const uint8_t* __restrict__ phib,
    const uint8_t* __restrict__ gshuf,
    const float* __restrict__ wW, const float* __restrict__ wb,
    float* __restrict__ out, float* __restrict__ stats)
{
    __shared__ float yl[16][32][33];   // 67.6 KB
    __shared__ float lred[16][32];
    __shared__ float lwW[2048];
    __shared__ float lwb[64];
    const int tid  = threadIdx.x;
    const int wave = tid >> 6;
    const int lane = tid & 63;
    const int h = lane >> 4;
    const int r = lane & 15;
    const int blk = blockIdx.x;
    const int b = blk >> 6;            // 64 q-blocks per batch
    const int q0 = (blk & 63) * 64;
    const int qh = wave >> 3;          // query half 0/1
    const int kq = wave & 7;           // key octant
    const int qbase = q0 + qh*32;
    const size_t base = (size_t)b * 4096;

    #pragma unroll
    for (int j = 0; j < 2; ++j) lwW[tid + 1024*j] = wW[tid + 1024*j];
    if (tid < 64) lwb[tid] = wb[tid];

    F8 qaA, qaB;
    qaA.v = *(const uint2*)(thetab + (base + qbase + r)*32 + h*8);
    qaB.v = *(const uint2*)(thetab + (base + qbase + 16 + r)*32 + h*8);
    const uint8_t* phiB = phib  + (size_t)b*131072;   // 128 chunks * 1024 B
    const uint8_t* gB   = gshuf + (size_t)b*131072;
    const int loff = (h*16 + r)*16;                   // lane slot in pair-pack

    f32x4 y0A = {0,0,0,0}, y1A = {0,0,0,0};
    f32x4 y0B = {0,0,0,0}, y1B = {0,0,0,0};
    float lsA = 0.f, lsB = 0.f;

    const int cbeg = kq * 16;          // first chunk of this octant

    auto QKEXP = [&](const uint4& kf, F8& pA_, F8& pB_) {
        F8 ka_, kb_;
        ka_.v.x = kf.x; ka_.v.y = kf.y;
        kb_.v.x = kf.z; kb_.v.y = kf.w;
        f32x4 z = {0,0,0,0};
        f32x4 s0A = __builtin_amdgcn_mfma_f32_16x16x32_fp8_fp8(ka_.ll, qaA.ll, z, 0, 0, 0);
        f32x4 s1A = __builtin_amdgcn_mfma_f32_16x16x32_fp8_fp8(kb_.ll, qaA.ll, z, 0, 0, 0);
        f32x4 s0B = __builtin_amdgcn_mfma_f32_16x16x32_fp8_fp8(ka_.ll, qaB.ll, z, 0, 0, 0);
        f32x4 s1B = __builtin_amdgcn_mfma_f32_16x16x32_fp8_fp8(kb_.ll, qaB.ll, z, 0, 0, 0);

        float pA0 = EXP2F(s0A[0]), pA1 = EXP2F(s0A[1]), pA2 = EXP2F(s0A[2]), pA3 = EXP2F(s0A[3]);
        float pA4 = EXP2F(s1A[0]), pA5 = EXP2F(s1A[1]), pA6 = EXP2F(s1A[2]), pA7 = EXP2F(s1A[3]);
        float pB0 = EXP2F(s0B[0]), pB1 = EXP2F(s0B[1]), pB2 = EXP2F(s0B[2]), pB3 = EXP2F(s0B[3]);
        float pB4 = EXP2F(s1B[0]), pB5 = EXP2F(s1B[1]), pB6 = EXP2F(s1B[2]), pB7 = EXP2F(s1B[3]);
        lsA += ((pA0+pA1)+(pA2+pA3)) + ((pA4+pA5)+(pA6+pA7));
        lsB += ((pB0+pB1)+(pB2+pB3)) + ((pB4+pB5)+(pB6+pB7));

        int lo = __builtin_amdgcn_cvt_pk_fp8_f32(pA0, pA1, 0, false);
        lo     = __builtin_amdgcn_cvt_pk_fp8_f32(pA2, pA3, lo, true);
        int hi = __builtin_amdgcn_cvt_pk_fp8_f32(pA4, pA5, 0, false);
        hi     = __builtin_amdgcn_cvt_pk_fp8_f32(pA6, pA7, hi, true);
        pA_.v.x = (uint32_t)lo; pA_.v.y = (uint32_t)hi;
        lo = __builtin_amdgcn_cvt_pk_fp8_f32(pB0, pB1, 0, false);
        lo = __builtin_amdgcn_cvt_pk_fp8_f32(pB2, pB3, lo, true);
        hi = __builtin_amdgcn_cvt_pk_fp8_f32(pB4, pB5, 0, false);
        hi = __builtin_amdgcn_cvt_pk_fp8_f32(pB6, pB7, hi, true);
        pB_.v.x = (uint32_t)lo; pB_.v.y = (uint32_t)hi;
    };

    auto PV = [&](const F8& pA_, const F8& pB_, const uint4& gf) {
        F8 g0_, g1_;
        g0_.v.x = gf.x; g0_.v.y = gf.y;
        g1_.v.x = gf.z; g1_.v.y = gf.w;
        y0A = __builtin_amdgcn_mfma_f32_16x16x32_fp8_fp8(pA_.ll, g0_.ll, y0A, 0, 0, 0);
        y1A = __builtin_amdgcn_mfma_f32_16x16x32_fp8_fp8(pA_.ll, g1_.ll, y1A, 0, 0, 0);
        y0B = __builtin_amdgcn_mfma_f32_16x16x32_fp8_fp8(pB_.ll, g0_.ll, y0B, 0, 0, 0);
        y1B = __builtin_amdgcn_mfma_f32_16x16x32_fp8_fp8(pB_.ll, g1_.ll, y1B, 0, 0, 0);
    };

    uint4 kC, kN, gP, gC, gN;
    kC = *(const uint4*)(phiB + (size_t)cbeg*1024 + loff);
    gP = *(const uint4*)(gB   + (size_t)cbeg*1024 + loff);
    kN = *(const uint4*)(phiB + (size_t)(cbeg + 1)*1024 + loff);
    gC = *(const uint4*)(gB   + (size_t)(cbeg + 1)*1024 + loff);

    F8 paA0, paB0;
    QKEXP(kC, paA0, paB0);             // chunk cbeg
    kC = kN;

    for (int t = 1; t < 16; ++t) {
        const int nc = (t + 1 < 16) ? cbeg + t + 1 : cbeg;   // dummy wrap at end
        kN = *(const uint4*)(phiB + (size_t)nc*1024 + loff);
        gN = *(const uint4*)(gB   + (size_t)nc*1024 + loff);

        PV(paA0, paB0, gP);            // PV for chunk t-1 (indep of this QK/exp)
        QKEXP(kC, paA0, paB0);         // QK + exp + pack for chunk t

        kC = kN;
        gP = gC; gC = gN;
    }
    PV(paA0, paB0, gP);                // epilogue: PV for chunk cbeg+15

    lsA += __shfl_xor(lsA, 16); lsA += __shfl_xor(lsA, 32);
    lsB += __shfl_xor(lsB, 16); lsB += __shfl_xor(lsB, 32);

    #pragma unroll
    for (int gi = 0; gi < 4; ++gi) {
        yl[wave][4*h+gi][r]       = y0A[gi];
        yl[wave][4*h+gi][16+r]    = y1A[gi];
        yl[wave][16+4*h+gi][r]    = y0B[gi];
        yl[wave][16+4*h+gi][16+r] = y1B[gi];
    }
    if (lane < 16) { lred[wave][r] = lsA; lred[wave][16+r] = lsB; }
    __syncthreads();

    // Phase B: combine 8 key-octant waves per query half + normalize.
    {
        const int q   = tid >> 4;
        const int d2  = (tid & 15) * 2;
        const int qh2 = q >> 5;
        const int ql  = q & 31;
        float a0=0.f, a1=0.f, lq=0.f;
        #pragma unroll
        for (int w = 0; w < 8; ++w) {
            a0 += yl[qh2*8+w][ql][d2];
            a1 += yl[qh2*8+w][ql][d2+1];
            lq += lred[qh2*8+w][ql];
        }
        float inv = 1.0f / lq;
        yl[qh2*8][ql][d2]   = a0*inv;
        yl[qh2*8][ql][d2+1] = a1*inv;
    }
    __syncthreads();

    // Phase C: w_y = y @ w_W + w_b -> out (pre-BN); channel sum/sumsq.
    {
        const int p   = lane;              // pixel within block (0..63)
        const int cg_ = wave;              // channel group (0..15)
        float acc[4];
        #pragma unroll
        for (int j = 0; j < 4; ++j) acc[j] = lwb[cg_*4 + j];
        for (int d = 0; d < 32; ++d) {
            float yv = yl[(p >> 5)*8][p & 31][d];
            #pragma unroll
            for (int j = 0; j < 4; ++j) acc[j] += yv * lwW[d*64 + cg_*4 + j];
        }
        *(float4*)(out + (size_t)(base + q0 + p)*64 + cg_*4) = *(float4*)&acc[0];

        float s1[4], s2[4];
        #pragma unroll
        for (int j = 0; j < 4; ++j) { s1[j] = acc[j]; s2[j] = acc[j]*acc[j]; }
        #pragma unroll
        for (int m = 1; m <= 32; m <<= 1) {
            #pragma unroll
            for (int j = 0; j < 4; ++j) {
                s1[j] += __shfl_xor(s1[j], m);
                s2[j] += __shfl_xor(s2[j], m);
            }
        }
        if (lane == 0) {                    // transposed: stats[stat_row][block]
            #pragma unroll
            for (int j = 0; j < 4; ++j) {
                stats[(size_t)(cg_*4 + j)*256 + blk]        = s1[j];
                stats[(size_t)(64 + cg_*4 + j)*256 + blk]   = s2[j];
            }
        }
    }
}

// ---------------------------------------------------------------------------
// Kernel 3: fused BN-finalize + apply (unchanged from R12/R14/R16).
// ---------------------------------------------------------------------------
__global__ __launch_bounds__(256) void apply_kernel(
    const float* __restrict__ stats,
    const float* __restrict__ gamma,
    const float* __restrict__ beta,
    const float* __restrict__ x,
    float* __restrict__ out)
{
    __shared__ float sums1[64];
    __shared__ float sums2[64];
    __shared__ __align__(16) float params[128];
    const int tid = threadIdx.x;
    {
        const int c = tid >> 2;        // 0..63
        const int part = tid & 3;      // 0..3 -> blocks part*64..+63
        const float4* st4 = (const float4*)stats;
        float s1 = 0.f, s2 = 0.f;
        #pragma unroll
        for (int j = 0; j < 16; ++j) {
            float4 v = st4[c*64 + part*16 + j];
            s1 += (v.x + v.y) + (v.z + v.w);
        }
        #pragma unroll
        for (int j = 0; j < 16; ++j) {
            float4 v = st4[(64 + c)*64 + part*16 + j];
            s2 += (v.x + v.y) + (v.z + v.w);
        }
        s1 += __shfl_xor(s1, 1); s1 += __shfl_xor(s1, 2);
        s2 += __shfl_xor(s2, 1); s2 += __shfl_xor(s2, 2);
        if (part == 0) { sums1[c] = s1; sums2[c] = s2; }
    }
    __syncthreads();
    if (tid < 64) {
        float mean = sums1[tid] * (1.0f/16384.0f);
        float var  = sums2[tid] * (1.0f/16384.0f) - mean*mean;
        float sc = gamma[tid] * rsqrtf(var + EPSV);
        params[tid]      = sc;
        params[64 + tid] = beta[tid] - mean*sc;
    }
    __syncthreads();

    const float4* x4 = (const float4*)x;
    float4* o4 = (float4*)out;
    #pragma unroll
    for (int j = 0; j < 4; ++j) {
        int i4 = blockIdx.x*1024 + tid + 256*j;   // 262144 float4s total
        int cb = (i4 & 15) * 4;
        float4 v  = o4[i4];
        float4 xv = x4[i4];
        float4 sc = *(const float4*)&params[cb];
        float4 sh = *(const float4*)&params[64 + cb];
        float4 rr;
        rr.x = xv.x + sc.x*v.x + sh.x;
        rr.y = xv.y + sc.y*v.y + sh.y;
        rr.z = xv.z + sc.z*v.z + sh.z;
        rr.w = xv.w + sc.w*v.w + sh.w;
        o4[i4] = rr;
    }
}

// ---------------------------------------------------------------------------
extern "C" void kernel_launch(void* const* d_in, const int* in_sizes, int n_in,
                              void* d_out, int out_size, void* d_ws, size_t ws_size,
                              hipStream_t stream)
{
    const float* x     = (const float*)d_in[0];
    const float* gW    = (const float*)d_in[1];
    const float* gb    = (const float*)d_in[2];
    const float* pW    = (const float*)d_in[3];
    const float* pb    = (const float*)d_in[4];
    const float* tW    = (const float*)d_in[5];
    const float* tb    = (const float*)d_in[6];
    const float* wW    = (const float*)d_in[7];
    const float* wb    = (const float*)d_in[8];
    const float* gamma = (const float*)d_in[9];
    const float* beta  = (const float*)d_in[10];
    float* out = (float*)d_out;

    char* w = (char*)d_ws;
    uint8_t* thetab = (uint8_t*)(w);                               // 512 KB
    uint8_t* phib   = (uint8_t*)(w + (1u<<19));                    // 512 KB
    uint8_t* gshuf  = (uint8_t*)(w + (2u<<19));                    // 512 KB
    float* stats    = (float*)(w + (3u<<19));                      // 128 KB

    proj_kernel<<<512, 256, 0, stream>>>(x, gW, gb, pW, pb, tW, tb, thetab, phib, gshuf);
    attn_kernel<<<256, 1024, 0, stream>>>(thetab, phib, gshuf, wW, wb, out, stats);
    apply_kernel<<<256, 256, 0, stream>>>(stats, gamma, beta, x, out);
}